// Round 1
// baseline (1218.038 us; speedup 1.0000x reference)
//
#include <hip/hip_runtime.h>
#include <math.h>

#define BB 4
#define SS 4096
#define DD 1024
#define TPp 16
#define TEe 64
#define DKk 128

// ---------------- Kernel A1: E = tp@Wt + bt ; T_scaled ; bqt = bq@T ----------------
__global__ __launch_bounds__(256) void temb_kernel(const float* __restrict__ tp,
                                                   const float* __restrict__ Wt,
                                                   const float* __restrict__ bt,
                                                   const float* __restrict__ bq,
                                                   float* __restrict__ Tws,
                                                   float* __restrict__ bqtws) {
  __shared__ float sE[TPp * DKk];   // 16x128
  __shared__ float sB[TPp];
  __shared__ float red[256];
  const int p = blockIdx.x, b = blockIdx.y;
  const int tid = threadIdx.x;
  float lsq = 0.f;
  for (int l = 0; l < 8; ++l) {
    int idx = tid + 256 * l;          // < 2048
    int i = idx >> 7, j = idx & 127;
    float a = bt[j];
    for (int c = 0; c < TEe; ++c)
      a += tp[((size_t)b * TPp + i) * TEe + c] * Wt[c * DKk + j];
    sE[idx] = a;
    lsq += a * a;
  }
  red[tid] = lsq;
  __syncthreads();
  for (int s2 = 128; s2 > 0; s2 >>= 1) {
    if (tid < s2) red[tid] += red[tid + s2];
    __syncthreads();
  }
  const float total = red[0];
  const float scale = (float)SS / (sqrtf((float)SS * total) + 1e-8f);
  if (tid < TPp) {
    float a = 0.f;
    for (int d2 = 0; d2 < DKk; ++d2) a += bq[d2] * sE[tid * DKk + d2];
    sB[tid] = a;
  }
  __syncthreads();
  // T[d,e] = scale * sum_t E[t,d]*E[t,e] ; this block handles 2048 of the 16384 entries
  for (int l = 0; l < 8; ++l) {
    int idx = p * 2048 + tid + 256 * l;
    int d2 = idx >> 7, e = idx & 127;
    float a = 0.f;
    #pragma unroll
    for (int t = 0; t < TPp; ++t) a += sE[t * DKk + d2] * sE[t * DKk + e];
    Tws[(size_t)b * DKk * DKk + idx] = scale * a;
  }
  if (p == 0 && tid < DKk) {
    float a = 0.f;
    #pragma unroll
    for (int t = 0; t < TPp; ++t) a += sB[t] * sE[t * DKk + tid];
    bqtws[b * DKk + tid] = scale * a;
  }
}

// ---------------- Kernel A2: Wqp[b] = Wq @ T[b]  (1024x128 per batch) ----------------
__global__ __launch_bounds__(128) void wqp_kernel(const float* __restrict__ Wq,
                                                  const float* __restrict__ Tws,
                                                  float* __restrict__ Wqp) {
  __shared__ float sW[DKk];
  const int m = blockIdx.x, b = blockIdx.y;
  const int e = threadIdx.x;
  sW[e] = Wq[(size_t)m * DKk + e];
  __syncthreads();
  const float* Tb = Tws + (size_t)b * DKk * DKk;
  float a = 0.f;
  #pragma unroll 8
  for (int d2 = 0; d2 < DKk; ++d2) a += sW[d2] * Tb[d2 * DKk + e];
  Wqp[((size_t)b * DD + m) * DKk + e] = a;
}

// ---------------- Kernel B: fused projection [16384x1024] @ [1024x384] -> QT,K,V ----
__global__ __launch_bounds__(256) void proj_kernel(const float* __restrict__ x,
                                                   const float* __restrict__ Wqp,
                                                   const float* __restrict__ bqt,
                                                   const float* __restrict__ Wk,
                                                   const float* __restrict__ bk,
                                                   const float* __restrict__ Wv,
                                                   const float* __restrict__ bv,
                                                   float* __restrict__ QT,
                                                   float* __restrict__ Kb,
                                                   float* __restrict__ Vb) {
  __shared__ float As[64 * 33];   // [row][k] padded
  __shared__ float Bs[32 * 68];   // [k][col] padded, float4-aligned rows
  const int mblk = blockIdx.x, nblk = blockIdx.y;
  const int rowbase = mblk * 64;
  const int b = rowbase >> 12;            // 4096 rows per batch; 64 | 4096
  const int region = nblk >> 1;           // 0:QT 1:K 2:V
  const int creg = (nblk & 1) * 64;       // col offset inside the 128-wide region
  const float* Wbase;
  const float* bias;
  float* outb;
  if (region == 0)      { Wbase = Wqp + (size_t)b * DD * DKk; bias = bqt + b * DKk; outb = QT; }
  else if (region == 1) { Wbase = Wk; bias = bk; outb = Kb; }
  else                  { Wbase = Wv; bias = bv; outb = Vb; }
  const int tid = threadIdx.x, tx = tid & 15, ty = tid >> 4;
  float acc[4][4] = {};
  for (int kt = 0; kt < 32; ++kt) {
    __syncthreads();
    for (int l = 0; l < 2; ++l) {
      int fidx = tid + 256 * l;           // < 512
      int r = fidx >> 3, k4 = fidx & 7;   // A tile: 64 rows x 8 float4
      float4 v = *(const float4*)&x[(size_t)(rowbase + r) * DD + kt * 32 + 4 * k4];
      As[r * 33 + 4 * k4 + 0] = v.x; As[r * 33 + 4 * k4 + 1] = v.y;
      As[r * 33 + 4 * k4 + 2] = v.z; As[r * 33 + 4 * k4 + 3] = v.w;
      int k = fidx >> 4, c4 = fidx & 15;  // B tile: 32 k x 16 float4
      *(float4*)&Bs[k * 68 + 4 * c4] =
          *(const float4*)&Wbase[(size_t)(kt * 32 + k) * DKk + creg + 4 * c4];
    }
    __syncthreads();
    #pragma unroll 8
    for (int k = 0; k < 32; ++k) {
      float av[4];
      for (int i = 0; i < 4; ++i) av[i] = As[(4 * ty + i) * 33 + k];
      float4 b4 = *(const float4*)&Bs[k * 68 + 4 * tx];
      float bvv[4] = {b4.x, b4.y, b4.z, b4.w};
      for (int i = 0; i < 4; ++i)
        for (int j = 0; j < 4; ++j) acc[i][j] += av[i] * bvv[j];
    }
  }
  float bb[4];
  for (int j = 0; j < 4; ++j) bb[j] = bias[creg + 4 * tx + j];
  for (int i = 0; i < 4; ++i) {
    float4 o = make_float4(acc[i][0] + bb[0], acc[i][1] + bb[1],
                           acc[i][2] + bb[2], acc[i][3] + bb[3]);
    *(float4*)&outb[(size_t)(rowbase + 4 * ty + i) * DKk + creg + 4 * tx] = o;
  }
}

// ---------------- Kernel C1: scores (raw, scaled) + online softmax m/l --------------
__global__ __launch_bounds__(256) void score_kernel(const float* __restrict__ QT,
                                                    const float* __restrict__ Kb,
                                                    float* __restrict__ attn,
                                                    float* __restrict__ mrow,
                                                    float* __restrict__ lrow) {
  __shared__ float QTs[128 * 66];  // [e][row] transposed, stride 66
  __shared__ float Ks[64 * 66];    // [e-half][col] transposed, stride 66
  const int b = blockIdx.y, rowbase = blockIdx.x * 64;
  const int tid = threadIdx.x, tx = tid & 15, ty = tid >> 4;
  const float* QTb = QT + (size_t)b * SS * DKk;
  const float* Kbb = Kb + (size_t)b * SS * DKk;
  float* attnb = attn + (size_t)b * SS * SS;
  for (int l = 0; l < 8; ++l) {
    int fidx = tid + 256 * l;            // < 2048
    int r = fidx >> 5, e4 = fidx & 31;
    const float4 v = *(const float4*)&QTb[(size_t)(rowbase + r) * DKk + 4 * e4];
    QTs[(4 * e4 + 0) * 66 + r] = v.x; QTs[(4 * e4 + 1) * 66 + r] = v.y;
    QTs[(4 * e4 + 2) * 66 + r] = v.z; QTs[(4 * e4 + 3) * 66 + r] = v.w;
  }
  float m_run[4], l_run[4];
  for (int i = 0; i < 4; ++i) { m_run[i] = -INFINITY; l_run[i] = 0.f; }
  const float sc = 0.088388347648318447f;  // 1/sqrt(128)
  for (int ct = 0; ct < 64; ++ct) {
    const int colbase = ct * 64;
    float acc[4][4] = {};
    for (int h = 0; h < 2; ++h) {
      __syncthreads();   // protect Ks while previous compute may still read it
      for (int l = 0; l < 4; ++l) {
        int fidx = tid + 256 * l;        // < 1024
        int c = fidx >> 4, e4 = fidx & 15;
        const float4 v =
            *(const float4*)&Kbb[(size_t)(colbase + c) * DKk + h * 64 + 4 * e4];
        Ks[(4 * e4 + 0) * 66 + c] = v.x; Ks[(4 * e4 + 1) * 66 + c] = v.y;
        Ks[(4 * e4 + 2) * 66 + c] = v.z; Ks[(4 * e4 + 3) * 66 + c] = v.w;
      }
      __syncthreads();
      #pragma unroll 4
      for (int e = 0; e < 64; ++e) {
        const float2 a01 = *(const float2*)&QTs[(h * 64 + e) * 66 + 4 * ty];
        const float2 a23 = *(const float2*)&QTs[(h * 64 + e) * 66 + 4 * ty + 2];
        const float2 b01 = *(const float2*)&Ks[e * 66 + 4 * tx];
        const float2 b23 = *(const float2*)&Ks[e * 66 + 4 * tx + 2];
        const float av[4] = {a01.x, a01.y, a23.x, a23.y};
        const float bv2[4] = {b01.x, b01.y, b23.x, b23.y};
        for (int i = 0; i < 4; ++i)
          for (int j = 0; j < 4; ++j) acc[i][j] += av[i] * bv2[j];
      }
    }
    for (int i = 0; i < 4; ++i) {
      float s0 = acc[i][0] * sc, s1 = acc[i][1] * sc;
      float s2 = acc[i][2] * sc, s3 = acc[i][3] * sc;
      float tmax = fmaxf(fmaxf(s0, s1), fmaxf(s2, s3));
      for (int off = 1; off < 16; off <<= 1) tmax = fmaxf(tmax, __shfl_xor(tmax, off));
      const float mnew = fmaxf(m_run[i], tmax);
      float psum = __expf(s0 - mnew) + __expf(s1 - mnew) +
                   __expf(s2 - mnew) + __expf(s3 - mnew);
      for (int off = 1; off < 16; off <<= 1) psum += __shfl_xor(psum, off);
      l_run[i] = l_run[i] * __expf(m_run[i] - mnew) + psum;
      m_run[i] = mnew;
      *(float4*)&attnb[(size_t)(rowbase + 4 * ty + i) * SS + colbase + 4 * tx] =
          make_float4(s0, s1, s2, s3);
    }
  }
  if (tx == 0) {
    for (int i = 0; i < 4; ++i) {
      mrow[b * SS + rowbase + 4 * ty + i] = m_run[i];
      lrow[b * SS + rowbase + 4 * ty + i] = l_run[i];
    }
  }
}

// ---------------- Kernel C2: normalize attn in place + out = attn @ V ----------------
__global__ __launch_bounds__(256) void pv_kernel(const float* __restrict__ Vb,
                                                 float* __restrict__ attn,
                                                 const float* __restrict__ mrow,
                                                 const float* __restrict__ lrow,
                                                 float* __restrict__ outp) {
  __shared__ float Ps[64 * 68];    // [col][row] transposed, stride 68 (f4-aligned)
  __shared__ float Vs[64 * 132];   // [col][d] natural, stride 132 (f4-aligned)
  const int b = blockIdx.y, rowbase = blockIdx.x * 64;
  const int tid = threadIdx.x, tx = tid & 15, ty = tid >> 4;
  const float* Vbb = Vb + (size_t)b * SS * DKk;
  float* attnb = attn + (size_t)b * SS * SS;
  float m_i[4], linv[4];
  for (int i = 0; i < 4; ++i) {
    m_i[i] = mrow[b * SS + rowbase + 4 * ty + i];
    linv[i] = 1.0f / lrow[b * SS + rowbase + 4 * ty + i];
  }
  float acc[4][8] = {};
  for (int ct = 0; ct < 64; ++ct) {
    const int colbase = ct * 64;
    __syncthreads();   // protect Ps/Vs from overwrite while previous compute reads
    for (int i = 0; i < 4; ++i) {
      float* ap = &attnb[(size_t)(rowbase + 4 * ty + i) * SS + colbase + 4 * tx];
      float4 s4 = *(const float4*)ap;
      float4 p4;
      p4.x = __expf(s4.x - m_i[i]) * linv[i];
      p4.y = __expf(s4.y - m_i[i]) * linv[i];
      p4.z = __expf(s4.z - m_i[i]) * linv[i];
      p4.w = __expf(s4.w - m_i[i]) * linv[i];
      *(float4*)ap = p4;
      Ps[(4 * tx + 0) * 68 + 4 * ty + i] = p4.x;
      Ps[(4 * tx + 1) * 68 + 4 * ty + i] = p4.y;
      Ps[(4 * tx + 2) * 68 + 4 * ty + i] = p4.z;
      Ps[(4 * tx + 3) * 68 + 4 * ty + i] = p4.w;
    }
    for (int l = 0; l < 8; ++l) {
      int fidx = tid + 256 * l;          // < 2048
      int c = fidx >> 5, d4 = fidx & 31;
      *(float4*)&Vs[c * 132 + 4 * d4] =
          *(const float4*)&Vbb[(size_t)(colbase + c) * DKk + 4 * d4];
    }
    __syncthreads();
    #pragma unroll 4
    for (int c = 0; c < 64; ++c) {
      float4 p4 = *(const float4*)&Ps[c * 68 + 4 * ty];
      float4 va = *(const float4*)&Vs[c * 132 + 4 * tx];
      float4 vb2 = *(const float4*)&Vs[c * 132 + 64 + 4 * tx];
      const float pv[4] = {p4.x, p4.y, p4.z, p4.w};
      const float vav[4] = {va.x, va.y, va.z, va.w};
      const float vbv[4] = {vb2.x, vb2.y, vb2.z, vb2.w};
      for (int i = 0; i < 4; ++i)
        for (int w = 0; w < 4; ++w) {
          acc[i][w]     += pv[i] * vav[w];
          acc[i][4 + w] += pv[i] * vbv[w];
        }
    }
  }
  for (int i = 0; i < 4; ++i) {
    const size_t ob = (size_t)(b * SS + rowbase + 4 * ty + i) * DKk;
    *(float4*)&outp[ob + 4 * tx] =
        make_float4(acc[i][0], acc[i][1], acc[i][2], acc[i][3]);
    *(float4*)&outp[ob + 64 + 4 * tx] =
        make_float4(acc[i][4], acc[i][5], acc[i][6], acc[i][7]);
  }
}

extern "C" void kernel_launch(void* const* d_in, const int* in_sizes, int n_in,
                              void* d_out, int out_size, void* d_ws, size_t ws_size,
                              hipStream_t stream) {
  const float* x  = (const float*)d_in[0];
  const float* tp = (const float*)d_in[1];
  const float* Wq = (const float*)d_in[2];
  const float* bq = (const float*)d_in[3];
  const float* Wk = (const float*)d_in[4];
  const float* bk = (const float*)d_in[5];
  const float* Wv = (const float*)d_in[6];
  const float* bv = (const float*)d_in[7];
  const float* Wt = (const float*)d_in[8];
  const float* bt = (const float*)d_in[9];
  float* out  = (float*)d_out;
  float* attn = out + (size_t)BB * SS * DKk;   // second output, concatenated
  float* ws = (float*)d_ws;
  // workspace layout (floats)
  float* Tws  = ws;                 // 4*128*128      = 65536
  float* bqt  = ws + 65536;         // 4*128          = 512
  float* Wqp  = ws + 66048;         // 4*1024*128     = 524288
  float* QT   = ws + 590336;        // 4*4096*128     = 2097152
  float* Kb   = ws + 2687488;       // 2097152
  float* Vb   = ws + 4784640;       // 2097152
  float* mrow = ws + 6881792;       // 16384
  float* lrow = ws + 6898176;       // 16384  (total 6914560 floats = 26.4 MiB)

  temb_kernel<<<dim3(8, 4), 256, 0, stream>>>(tp, Wt, bt, bq, Tws, bqt);
  wqp_kernel<<<dim3(1024, 4), 128, 0, stream>>>(Wq, Tws, Wqp);
  proj_kernel<<<dim3(256, 6), 256, 0, stream>>>(x, Wqp, bqt, Wk, bk, Wv, bv, QT, Kb, Vb);
  score_kernel<<<dim3(64, 4), 256, 0, stream>>>(QT, Kb, attn, mrow, lrow);
  pv_kernel<<<dim3(64, 4), 256, 0, stream>>>(Vb, attn, mrow, lrow, out);
}

// Round 2
// 1001.360 us; speedup vs baseline: 1.2164x; 1.2164x over previous
//
#include <hip/hip_runtime.h>
#include <math.h>

#define BB 4
#define SS 4096
#define DD 1024
#define TPp 16
#define TEe 64
#define DKk 128

typedef __attribute__((ext_vector_type(8))) short short8;
typedef __attribute__((ext_vector_type(4))) float floatx4;
typedef __attribute__((ext_vector_type(16))) float floatx16;

// bf16 helpers (RNE, branchless; inputs are well-behaved, no NaN handling needed)
static __device__ inline short f2bf(float f) {
  union { float f; unsigned u; } v; v.f = f;
  unsigned r = v.u + 0x7fff + ((v.u >> 16) & 1);
  return (short)(r >> 16);
}
static __device__ inline float bf2f(short s) {
  union { unsigned u; float f; } v; v.u = ((unsigned)(unsigned short)s) << 16;
  return v.f;
}

// ---------------- Kernel A1: E = tp@Wt + bt ; T_scaled ; bqt = bq@T ----------------
__global__ __launch_bounds__(256) void temb_kernel(const float* __restrict__ tp,
                                                   const float* __restrict__ Wt,
                                                   const float* __restrict__ bt,
                                                   const float* __restrict__ bq,
                                                   float* __restrict__ Tws,
                                                   float* __restrict__ bqtws) {
  __shared__ float sE[TPp * DKk];   // 16x128
  __shared__ float sB[TPp];
  __shared__ float red[256];
  const int p = blockIdx.x, b = blockIdx.y;
  const int tid = threadIdx.x;
  float lsq = 0.f;
  for (int l = 0; l < 8; ++l) {
    int idx = tid + 256 * l;          // < 2048
    int i = idx >> 7, j = idx & 127;
    float a = bt[j];
    for (int c = 0; c < TEe; ++c)
      a += tp[((size_t)b * TPp + i) * TEe + c] * Wt[c * DKk + j];
    sE[idx] = a;
    lsq += a * a;
  }
  red[tid] = lsq;
  __syncthreads();
  for (int s2 = 128; s2 > 0; s2 >>= 1) {
    if (tid < s2) red[tid] += red[tid + s2];
    __syncthreads();
  }
  const float total = red[0];
  const float scale = (float)SS / (sqrtf((float)SS * total) + 1e-8f);
  if (tid < TPp) {
    float a = 0.f;
    for (int d2 = 0; d2 < DKk; ++d2) a += bq[d2] * sE[tid * DKk + d2];
    sB[tid] = a;
  }
  __syncthreads();
  for (int l = 0; l < 8; ++l) {
    int idx = p * 2048 + tid + 256 * l;
    int d2 = idx >> 7, e = idx & 127;
    float a = 0.f;
    #pragma unroll
    for (int t = 0; t < TPp; ++t) a += sE[t * DKk + d2] * sE[t * DKk + e];
    Tws[(size_t)b * DKk * DKk + idx] = scale * a;
  }
  if (p == 0 && tid < DKk) {
    float a = 0.f;
    #pragma unroll
    for (int t = 0; t < TPp; ++t) a += sB[t] * sE[t * DKk + tid];
    bqtws[b * DKk + tid] = scale * a;
  }
}

// ---------------- Kernel A2: Wqp[b] = Wq @ T[b]  (1024x128 per batch) ----------------
__global__ __launch_bounds__(128) void wqp_kernel(const float* __restrict__ Wq,
                                                  const float* __restrict__ Tws,
                                                  float* __restrict__ Wqp) {
  __shared__ float sW[DKk];
  const int m = blockIdx.x, b = blockIdx.y;
  const int e = threadIdx.x;
  sW[e] = Wq[(size_t)m * DKk + e];
  __syncthreads();
  const float* Tb = Tws + (size_t)b * DKk * DKk;
  float a = 0.f;
  #pragma unroll 8
  for (int d2 = 0; d2 < DKk; ++d2) a += sW[d2] * Tb[d2 * DKk + e];
  Wqp[((size_t)b * DD + m) * DKk + e] = a;
}

// ---------------- Kernel B: fused projection -> QT(hi/lo bf16), K(hi/lo bf16), V^T bf16
__global__ __launch_bounds__(256) void proj_kernel(const float* __restrict__ x,
                                                   const float* __restrict__ Wqp,
                                                   const float* __restrict__ bqt,
                                                   const float* __restrict__ Wk,
                                                   const float* __restrict__ bk,
                                                   const float* __restrict__ Wv,
                                                   const float* __restrict__ bv,
                                                   short* __restrict__ QTh,
                                                   short* __restrict__ QTl,
                                                   short* __restrict__ Kh,
                                                   short* __restrict__ Kl,
                                                   short* __restrict__ VT) {
  __shared__ float As[64 * 33];   // [row][k] padded
  __shared__ float Bs[32 * 68];   // [k][col] padded, float4-aligned rows
  const int mblk = blockIdx.x, nblk = blockIdx.y;
  const int rowbase = mblk * 64;
  const int b = rowbase >> 12;            // 4096 rows per batch
  const int region = nblk >> 1;           // 0:QT 1:K 2:V
  const int creg = (nblk & 1) * 64;       // col offset inside the 128-wide region
  const float* Wbase;
  const float* bias;
  if (region == 0)      { Wbase = Wqp + (size_t)b * DD * DKk; bias = bqt + b * DKk; }
  else if (region == 1) { Wbase = Wk; bias = bk; }
  else                  { Wbase = Wv; bias = bv; }
  const int tid = threadIdx.x, tx = tid & 15, ty = tid >> 4;
  float acc[4][4] = {};
  for (int kt = 0; kt < 32; ++kt) {
    __syncthreads();
    for (int l = 0; l < 2; ++l) {
      int fidx = tid + 256 * l;           // < 512
      int r = fidx >> 3, k4 = fidx & 7;   // A tile: 64 rows x 8 float4
      float4 v = *(const float4*)&x[(size_t)(rowbase + r) * DD + kt * 32 + 4 * k4];
      As[r * 33 + 4 * k4 + 0] = v.x; As[r * 33 + 4 * k4 + 1] = v.y;
      As[r * 33 + 4 * k4 + 2] = v.z; As[r * 33 + 4 * k4 + 3] = v.w;
      int k = fidx >> 4, c4 = fidx & 15;  // B tile: 32 k x 16 float4
      *(float4*)&Bs[k * 68 + 4 * c4] =
          *(const float4*)&Wbase[(size_t)(kt * 32 + k) * DKk + creg + 4 * c4];
    }
    __syncthreads();
    #pragma unroll 8
    for (int k = 0; k < 32; ++k) {
      float av[4];
      for (int i = 0; i < 4; ++i) av[i] = As[(4 * ty + i) * 33 + k];
      float4 b4 = *(const float4*)&Bs[k * 68 + 4 * tx];
      float bvv[4] = {b4.x, b4.y, b4.z, b4.w};
      for (int i = 0; i < 4; ++i)
        for (int j = 0; j < 4; ++j) acc[i][j] += av[i] * bvv[j];
    }
  }
  float bb[4];
  for (int j = 0; j < 4; ++j) bb[j] = bias[creg + 4 * tx + j];
  if (region <= 1) {
    short* Hp = (region == 0) ? QTh : Kh;
    short* Lp = (region == 0) ? QTl : Kl;
    for (int i = 0; i < 4; ++i) {
      short h[4], l[4];
      for (int j = 0; j < 4; ++j) {
        float v = acc[i][j] + bb[j];
        short hh = f2bf(v);
        h[j] = hh;
        l[j] = f2bf(v - bf2f(hh));
      }
      size_t off = (size_t)(rowbase + 4 * ty + i) * DKk + creg + 4 * tx;
      *(short4*)&Hp[off] = make_short4(h[0], h[1], h[2], h[3]);
      *(short4*)&Lp[off] = make_short4(l[0], l[1], l[2], l[3]);
    }
  } else {
    // V^T bf16: [b][n=128][t=4096]
    const int tloc = rowbase & 4095;
    for (int j = 0; j < 4; ++j) {
      short t4[4];
      for (int i = 0; i < 4; ++i) t4[i] = f2bf(acc[i][j] + bb[j]);
      *(short4*)&VT[((size_t)b * DKk + creg + 4 * tx + j) * SS + tloc + 4 * ty] =
          make_short4(t4[0], t4[1], t4[2], t4[3]);
    }
  }
}

// ---------------- Kernel C1: MFMA scores (split bf16) + raw write + m/linv -----------
// 32x32x16 bf16 MFMA. A[m=lane&31][k=(lane>>5)*8+j], B[k=(lane>>5)*8+j][n=lane&31],
// C/D: col=lane&31, row=(reg&3)+8*(reg>>2)+4*(lane>>5).
__global__ __launch_bounds__(256, 2) void score_kernel(const short* __restrict__ QTh,
                                                       const short* __restrict__ QTl,
                                                       const short* __restrict__ Kh,
                                                       const short* __restrict__ Kl,
                                                       float* __restrict__ attn,
                                                       float* __restrict__ mrow,
                                                       float* __restrict__ linv) {
  __shared__ float smM[4][32], smL[4][32];
  const int b = blockIdx.y, rowbase = blockIdx.x * 32;
  const int tid = threadIdx.x;
  const int wave = tid >> 6, lane = tid & 63;
  const int l31 = lane & 31, half = lane >> 5;
  const float sc = 0.088388347648318447f;  // 1/sqrt(128)
  // A fragments: QT hi/lo for 32 rows, K-dim 128 = 8 ksteps of 16
  const size_t qoff = ((size_t)b * SS + rowbase + l31) * DKk + half * 8;
  short8 aH[8], aL[8];
  #pragma unroll
  for (int ks = 0; ks < 8; ++ks) {
    aH[ks] = *(const short8*)(QTh + qoff + ks * 16);
    aL[ks] = *(const short8*)(QTl + qoff + ks * 16);
  }
  float m_r[16], l_r[16];
  #pragma unroll
  for (int r = 0; r < 16; ++r) { m_r[r] = -INFINITY; l_r[r] = 0.f; }
  float* attnb = attn + (size_t)b * SS * SS;
  float* srowbase = attnb + (size_t)rowbase * SS + l31;
  for (int ct = wave; ct < 128; ct += 4) {
    const int colbase = ct * 32;
    const size_t koff = ((size_t)b * SS + colbase + l31) * DKk + half * 8;
    floatx16 acc;
    #pragma unroll
    for (int r = 0; r < 16; ++r) acc[r] = 0.f;
    #pragma unroll
    for (int ks = 0; ks < 8; ++ks) {
      short8 bh = *(const short8*)(Kh + koff + ks * 16);
      short8 bl = *(const short8*)(Kl + koff + ks * 16);
      acc = __builtin_amdgcn_mfma_f32_32x32x16_bf16(aH[ks], bh, acc, 0, 0, 0);
      acc = __builtin_amdgcn_mfma_f32_32x32x16_bf16(aH[ks], bl, acc, 0, 0, 0);
      acc = __builtin_amdgcn_mfma_f32_32x32x16_bf16(aL[ks], bh, acc, 0, 0, 0);
    }
    float* srow = srowbase + colbase;
    #pragma unroll
    for (int reg = 0; reg < 16; ++reg) {
      const int row = (reg & 3) + 8 * (reg >> 2) + 4 * half;
      const float s = acc[reg] * sc;
      srow[(size_t)row * SS] = s;
      const float mn = fmaxf(m_r[reg], s);
      l_r[reg] = l_r[reg] * __expf(m_r[reg] - mn) + __expf(s - mn);
      m_r[reg] = mn;
    }
  }
  // reduce m/l across the 32 lanes of each half (cols)
  #pragma unroll
  for (int off = 1; off < 32; off <<= 1) {
    #pragma unroll
    for (int reg = 0; reg < 16; ++reg) {
      const float mo = __shfl_xor(m_r[reg], off, 64);
      const float lo = __shfl_xor(l_r[reg], off, 64);
      const float mn = fmaxf(m_r[reg], mo);
      l_r[reg] = l_r[reg] * __expf(m_r[reg] - mn) + lo * __expf(mo - mn);
      m_r[reg] = mn;
    }
  }
  if (l31 == 0) {
    #pragma unroll
    for (int reg = 0; reg < 16; ++reg) {
      const int row = (reg & 3) + 8 * (reg >> 2) + 4 * half;
      smM[wave][row] = m_r[reg];
      smL[wave][row] = l_r[reg];
    }
  }
  __syncthreads();
  if (tid < 32) {
    float m = smM[0][tid], l = smL[0][tid];
    #pragma unroll
    for (int w = 1; w < 4; ++w) {
      const float mo = smM[w][tid], lo = smL[w][tid];
      const float mn = fmaxf(m, mo);
      l = l * __expf(m - mn) + lo * __expf(mo - mn);
      m = mn;
    }
    mrow[b * SS + rowbase + tid] = m;
    linv[b * SS + rowbase + tid] = 1.0f / l;
  }
}

// ---------------- Kernel C2: normalize attn in place + out = P @ V (MFMA bf16) -------
// 16x16x32 bf16. A[m=lane&15][t=quad*8+j] comes straight from the raw-score row
// (global round-trip does the C->A layout transform). B[t=quad*8+j][n=lane&15] is a
// contiguous 16B read of V^T. C/D: row=quad*4+reg, col=lane&15.
__global__ __launch_bounds__(512, 2) void pv_kernel(const short* __restrict__ VT,
                                                    float* __restrict__ attn,
                                                    const float* __restrict__ mrow,
                                                    const float* __restrict__ linv,
                                                    float* __restrict__ outp) {
  __shared__ float sAcc[4][16][128];  // 32 KB partial-out exchange
  const int b = blockIdx.y, rowbase = blockIdx.x * 64;
  const int tid = threadIdx.x, wave = tid >> 6, lane = tid & 63;
  const int wg = wave & 3, th = wave >> 2;
  const int l15 = lane & 15, quad = lane >> 4;
  const int row = rowbase + wg * 16 + l15;
  const float m_i = mrow[b * SS + row];
  const float li = linv[b * SS + row];
  float* arow = attn + (size_t)b * SS * SS + (size_t)row * SS + quad * 8;
  const short* vtb = VT + (size_t)b * DKk * SS + quad * 8;
  floatx4 acc[8];
  #pragma unroll
  for (int nt = 0; nt < 8; ++nt)
    #pragma unroll
    for (int r = 0; r < 4; ++r) acc[nt][r] = 0.f;
  for (int ct = th; ct < 128; ct += 2) {
    const int t0 = ct * 32;
    float4 s0 = *(const float4*)(arow + t0);
    float4 s1 = *(const float4*)(arow + t0 + 4);
    float p[8];
    p[0] = __expf(s0.x - m_i) * li; p[1] = __expf(s0.y - m_i) * li;
    p[2] = __expf(s0.z - m_i) * li; p[3] = __expf(s0.w - m_i) * li;
    p[4] = __expf(s1.x - m_i) * li; p[5] = __expf(s1.y - m_i) * li;
    p[6] = __expf(s1.z - m_i) * li; p[7] = __expf(s1.w - m_i) * li;
    *(float4*)(arow + t0) = make_float4(p[0], p[1], p[2], p[3]);
    *(float4*)(arow + t0 + 4) = make_float4(p[4], p[5], p[6], p[7]);
    short8 a;
    #pragma unroll
    for (int j = 0; j < 8; ++j) a[j] = f2bf(p[j]);
    #pragma unroll
    for (int nt = 0; nt < 8; ++nt) {
      short8 bf = *(const short8*)(vtb + (size_t)(nt * 16 + l15) * SS + t0);
      acc[nt] = __builtin_amdgcn_mfma_f32_16x16x32_bf16(a, bf, acc[nt], 0, 0, 0);
    }
  }
  if (th == 1) {
    #pragma unroll
    for (int nt = 0; nt < 8; ++nt)
      #pragma unroll
      for (int r = 0; r < 4; ++r)
        sAcc[wg][quad * 4 + r][nt * 16 + l15] = acc[nt][r];
  }
  __syncthreads();
  if (th == 0) {
    #pragma unroll
    for (int nt = 0; nt < 8; ++nt)
      #pragma unroll
      for (int r = 0; r < 4; ++r) {
        const int rr = quad * 4 + r, cc = nt * 16 + l15;
        outp[((size_t)b * SS + rowbase + wg * 16 + rr) * DKk + cc] =
            acc[nt][r] + sAcc[wg][rr][cc];
      }
  }
}

extern "C" void kernel_launch(void* const* d_in, const int* in_sizes, int n_in,
                              void* d_out, int out_size, void* d_ws, size_t ws_size,
                              hipStream_t stream) {
  const float* x  = (const float*)d_in[0];
  const float* tp = (const float*)d_in[1];
  const float* Wq = (const float*)d_in[2];
  const float* bq = (const float*)d_in[3];
  const float* Wk = (const float*)d_in[4];
  const float* bk = (const float*)d_in[5];
  const float* Wv = (const float*)d_in[6];
  const float* bv = (const float*)d_in[7];
  const float* Wt = (const float*)d_in[8];
  const float* bt = (const float*)d_in[9];
  float* out  = (float*)d_out;
  float* attn = out + (size_t)BB * SS * DKk;   // second output, concatenated
  float* ws = (float*)d_ws;
  // workspace layout (float offsets); bf16 arrays are 2M shorts = 1M floats each
  float* Tws  = ws;                         // 65536
  float* bqt  = ws + 65536;                 // 512
  float* Wqp  = ws + 66048;                 // 524288
  short* QTh  = (short*)(ws + 590336);      // 1048576 floats
  short* QTl  = (short*)(ws + 1638912);
  short* Kh   = (short*)(ws + 2687488);
  short* Kl   = (short*)(ws + 3736064);
  short* VT   = (short*)(ws + 4784640);
  float* mrow = ws + 5833216;               // 16384
  float* lin  = ws + 5849600;               // 16384  -> total 5865984 fl = 23.5 MiB

  temb_kernel<<<dim3(8, 4), 256, 0, stream>>>(tp, Wt, bt, bq, Tws, bqt);
  wqp_kernel<<<dim3(1024, 4), 128, 0, stream>>>(Wq, Tws, Wqp);
  proj_kernel<<<dim3(256, 6), 256, 0, stream>>>(x, Wqp, bqt, Wk, bk, Wv, bv,
                                                QTh, QTl, Kh, Kl, VT);
  score_kernel<<<dim3(128, 4), 256, 0, stream>>>(QTh, QTl, Kh, Kl, attn, mrow, lin);
  pv_kernel<<<dim3(64, 4), 512, 0, stream>>>(VT, attn, mrow, lin, out);
}

// Round 3
// 820.484 us; speedup vs baseline: 1.4845x; 1.2205x over previous
//
#include <hip/hip_runtime.h>
#include <math.h>

#define BB 4
#define SS 4096
#define DD 1024
#define TPp 16
#define TEe 64
#define DKk 128

typedef __attribute__((ext_vector_type(8))) short short8;
typedef __attribute__((ext_vector_type(4))) float floatx4;
typedef __attribute__((ext_vector_type(16))) float floatx16;

#define BSTRIDE 524288  // 4096*128 shorts per batch for frag-layout arrays

// bf16 helpers (RNE, branchless)
static __device__ inline short f2bf(float f) {
  union { float f; unsigned u; } v; v.f = f;
  unsigned r = v.u + 0x7fff + ((v.u >> 16) & 1);
  return (short)(r >> 16);
}
static __device__ inline float bf2f(short s) {
  union { unsigned u; float f; } v; v.u = ((unsigned)(unsigned short)s) << 16;
  return v.f;
}

// ---------------- Kernel A1: E = tp@Wt + bt ; T_scaled ; bqt = bq@T ----------------
__global__ __launch_bounds__(256) void temb_kernel(const float* __restrict__ tp,
                                                   const float* __restrict__ Wt,
                                                   const float* __restrict__ bt,
                                                   const float* __restrict__ bq,
                                                   float* __restrict__ Tws,
                                                   float* __restrict__ bqtws) {
  __shared__ float sE[TPp * DKk];
  __shared__ float sB[TPp];
  __shared__ float red[256];
  const int p = blockIdx.x, b = blockIdx.y;
  const int tid = threadIdx.x;
  float lsq = 0.f;
  for (int l = 0; l < 8; ++l) {
    int idx = tid + 256 * l;
    int i = idx >> 7, j = idx & 127;
    float a = bt[j];
    for (int c = 0; c < TEe; ++c)
      a += tp[((size_t)b * TPp + i) * TEe + c] * Wt[c * DKk + j];
    sE[idx] = a;
    lsq += a * a;
  }
  red[tid] = lsq;
  __syncthreads();
  for (int s2 = 128; s2 > 0; s2 >>= 1) {
    if (tid < s2) red[tid] += red[tid + s2];
    __syncthreads();
  }
  const float total = red[0];
  const float scale = (float)SS / (sqrtf((float)SS * total) + 1e-8f);
  if (tid < TPp) {
    float a = 0.f;
    for (int d2 = 0; d2 < DKk; ++d2) a += bq[d2] * sE[tid * DKk + d2];
    sB[tid] = a;
  }
  __syncthreads();
  for (int l = 0; l < 8; ++l) {
    int idx = p * 2048 + tid + 256 * l;
    int d2 = idx >> 7, e = idx & 127;
    float a = 0.f;
    #pragma unroll
    for (int t = 0; t < TPp; ++t) a += sE[t * DKk + d2] * sE[t * DKk + e];
    Tws[(size_t)b * DKk * DKk + idx] = scale * a;
  }
  if (p == 0 && tid < DKk) {
    float a = 0.f;
    #pragma unroll
    for (int t = 0; t < TPp; ++t) a += sB[t] * sE[t * DKk + tid];
    bqtws[b * DKk + tid] = scale * a;
  }
}

// ---------------- Kernel A2: Wqp[b] = Wq @ T[b] ----------------
__global__ __launch_bounds__(128) void wqp_kernel(const float* __restrict__ Wq,
                                                  const float* __restrict__ Tws,
                                                  float* __restrict__ Wqp) {
  __shared__ float sW[DKk];
  const int m = blockIdx.x, b = blockIdx.y;
  const int e = threadIdx.x;
  sW[e] = Wq[(size_t)m * DKk + e];
  __syncthreads();
  const float* Tb = Tws + (size_t)b * DKk * DKk;
  float a = 0.f;
  #pragma unroll 8
  for (int d2 = 0; d2 < DKk; ++d2) a += sW[d2] * Tb[d2 * DKk + e];
  Wqp[((size_t)b * DD + m) * DKk + e] = a;
}

// ---------------- Kernel B: fused projection -> frag-layout QT/K (hi/lo), V ---------
// QT/K frag layout (32x32x16 A/B operand): off(t,f) =
//   ((t>>5)*8 + (f>>4))*512 + (((f>>3)&1)*32 + (t&31))*8 + (f&7)
// V frag layout (16x16x32 B operand): off(t,n) =
//   ((t>>5)*8 + (n>>4))*512 + (((t>>3)&3)*16 + (n&15))*8 + (t&7)
__global__ __launch_bounds__(256) void proj_kernel(const float* __restrict__ x,
                                                   const float* __restrict__ Wqp,
                                                   const float* __restrict__ bqt,
                                                   const float* __restrict__ Wk,
                                                   const float* __restrict__ bk,
                                                   const float* __restrict__ Wv,
                                                   const float* __restrict__ bv,
                                                   short* __restrict__ QTh,
                                                   short* __restrict__ QTl,
                                                   short* __restrict__ Kh,
                                                   short* __restrict__ Kl,
                                                   short* __restrict__ VT) {
  __shared__ float As[64 * 33];
  __shared__ float Bs[32 * 68];
  const int mblk = blockIdx.x, nblk = blockIdx.y;
  const int rowbase = mblk * 64;
  const int b = rowbase >> 12;
  const int region = nblk >> 1;           // 0:QT 1:K 2:V
  const int creg = (nblk & 1) * 64;
  const float* Wbase;
  const float* bias;
  if (region == 0)      { Wbase = Wqp + (size_t)b * DD * DKk; bias = bqt + b * DKk; }
  else if (region == 1) { Wbase = Wk; bias = bk; }
  else                  { Wbase = Wv; bias = bv; }
  const int tid = threadIdx.x, tx = tid & 15, ty = tid >> 4;
  float acc[4][4] = {};
  for (int kt = 0; kt < 32; ++kt) {
    __syncthreads();
    for (int l = 0; l < 2; ++l) {
      int fidx = tid + 256 * l;
      int r = fidx >> 3, k4 = fidx & 7;
      float4 v = *(const float4*)&x[(size_t)(rowbase + r) * DD + kt * 32 + 4 * k4];
      As[r * 33 + 4 * k4 + 0] = v.x; As[r * 33 + 4 * k4 + 1] = v.y;
      As[r * 33 + 4 * k4 + 2] = v.z; As[r * 33 + 4 * k4 + 3] = v.w;
      int k = fidx >> 4, c4 = fidx & 15;
      *(float4*)&Bs[k * 68 + 4 * c4] =
          *(const float4*)&Wbase[(size_t)(kt * 32 + k) * DKk + creg + 4 * c4];
    }
    __syncthreads();
    #pragma unroll 8
    for (int k = 0; k < 32; ++k) {
      float av[4];
      for (int i = 0; i < 4; ++i) av[i] = As[(4 * ty + i) * 33 + k];
      float4 b4 = *(const float4*)&Bs[k * 68 + 4 * tx];
      float bvv[4] = {b4.x, b4.y, b4.z, b4.w};
      for (int i = 0; i < 4; ++i)
        for (int j = 0; j < 4; ++j) acc[i][j] += av[i] * bvv[j];
    }
  }
  float bb[4];
  for (int j = 0; j < 4; ++j) bb[j] = bias[creg + 4 * tx + j];
  if (region <= 1) {
    short* Hp = (region == 0) ? QTh : Kh;
    short* Lp = (region == 0) ? QTl : Kl;
    const int f0 = creg + 4 * tx;
    const int ks0 = f0 >> 4, half0 = (f0 >> 3) & 1, j0 = f0 & 7;
    for (int i = 0; i < 4; ++i) {
      const int tloc = (rowbase & 4095) + 4 * ty + i;
      short h[4], l[4];
      for (int j = 0; j < 4; ++j) {
        float v = acc[i][j] + bb[j];
        short hh = f2bf(v);
        h[j] = hh;
        l[j] = f2bf(v - bf2f(hh));
      }
      const size_t off = (size_t)b * BSTRIDE +
          (size_t)((tloc >> 5) * 8 + ks0) * 512 + (half0 * 32 + (tloc & 31)) * 8 + j0;
      *(short4*)&Hp[off] = make_short4(h[0], h[1], h[2], h[3]);
      *(short4*)&Lp[off] = make_short4(l[0], l[1], l[2], l[3]);
    }
  } else {
    const int t0 = rowbase + 4 * ty;         // 4 consecutive t (i=0..3)
    const int tloc = t0 & 4095;
    const int ct = tloc >> 5, quad0 = (tloc >> 3) & 3, j0 = tloc & 7;
    for (int j = 0; j < 4; ++j) {
      const int n = creg + 4 * tx + j;
      short t4[4];
      for (int i = 0; i < 4; ++i) t4[i] = f2bf(acc[i][j] + bb[j]);
      const size_t off = (size_t)b * BSTRIDE +
          (size_t)(ct * 8 + (n >> 4)) * 512 + (quad0 * 16 + (n & 15)) * 8 + j0;
      *(short4*)&VT[off] = make_short4(t4[0], t4[1], t4[2], t4[3]);
    }
  }
}

// ---------------- Kernel C1: MFMA scores (split bf16) + raw write + m/linv -----------
// Frag loads are contiguous 1KB wave loads: base + lane*8 shorts.
__global__ __launch_bounds__(256, 2) void score_kernel(const short* __restrict__ QTh,
                                                       const short* __restrict__ QTl,
                                                       const short* __restrict__ Kh,
                                                       const short* __restrict__ Kl,
                                                       float* __restrict__ attn,
                                                       float* __restrict__ mrow,
                                                       float* __restrict__ linv) {
  __shared__ float smM[4][32], smL[4][32];
  const int b = blockIdx.y, rowbase = blockIdx.x * 32;
  const int tid = threadIdx.x;
  const int wave = tid >> 6, lane = tid & 63;
  const int l31 = lane & 31, half = lane >> 5;
  const float sc = 0.088388347648318447f;  // 1/sqrt(128)
  // A fragments: frag layout, tile = blockIdx.x
  const size_t qbase = (size_t)b * BSTRIDE + (size_t)blockIdx.x * 4096 + lane * 8;
  short8 aH[8], aL[8];
  #pragma unroll
  for (int ks = 0; ks < 8; ++ks) {
    aH[ks] = *(const short8*)(QTh + qbase + ks * 512);
    aL[ks] = *(const short8*)(QTl + qbase + ks * 512);
  }
  float m_r[16], l_r[16];
  #pragma unroll
  for (int r = 0; r < 16; ++r) { m_r[r] = -INFINITY; l_r[r] = 0.f; }
  float* attnb = attn + (size_t)b * SS * SS;
  float* srowbase = attnb + (size_t)rowbase * SS + l31;
  for (int ct = wave; ct < 128; ct += 4) {
    const int colbase = ct * 32;
    const size_t kbase = (size_t)b * BSTRIDE + (size_t)ct * 4096 + lane * 8;
    floatx16 acc;
    #pragma unroll
    for (int r = 0; r < 16; ++r) acc[r] = 0.f;
    #pragma unroll
    for (int ks = 0; ks < 8; ++ks) {
      short8 bh = *(const short8*)(Kh + kbase + ks * 512);
      short8 bl = *(const short8*)(Kl + kbase + ks * 512);
      acc = __builtin_amdgcn_mfma_f32_32x32x16_bf16(aH[ks], bh, acc, 0, 0, 0);
      acc = __builtin_amdgcn_mfma_f32_32x32x16_bf16(aH[ks], bl, acc, 0, 0, 0);
      acc = __builtin_amdgcn_mfma_f32_32x32x16_bf16(aL[ks], bh, acc, 0, 0, 0);
    }
    float* srow = srowbase + colbase;
    #pragma unroll
    for (int reg = 0; reg < 16; ++reg) {
      const int row = (reg & 3) + 8 * (reg >> 2) + 4 * half;
      const float s = acc[reg] * sc;
      srow[(size_t)row * SS] = s;
      const float mn = fmaxf(m_r[reg], s);
      l_r[reg] = l_r[reg] * __expf(m_r[reg] - mn) + __expf(s - mn);
      m_r[reg] = mn;
    }
  }
  #pragma unroll
  for (int off = 1; off < 32; off <<= 1) {
    #pragma unroll
    for (int reg = 0; reg < 16; ++reg) {
      const float mo = __shfl_xor(m_r[reg], off, 64);
      const float lo = __shfl_xor(l_r[reg], off, 64);
      const float mn = fmaxf(m_r[reg], mo);
      l_r[reg] = l_r[reg] * __expf(m_r[reg] - mn) + lo * __expf(mo - mn);
      m_r[reg] = mn;
    }
  }
  if (l31 == 0) {
    #pragma unroll
    for (int reg = 0; reg < 16; ++reg) {
      const int row = (reg & 3) + 8 * (reg >> 2) + 4 * half;
      smM[wave][row] = m_r[reg];
      smL[wave][row] = l_r[reg];
    }
  }
  __syncthreads();
  if (tid < 32) {
    float m = smM[0][tid], l = smL[0][tid];
    #pragma unroll
    for (int w = 1; w < 4; ++w) {
      const float mo = smM[w][tid], lo = smL[w][tid];
      const float mn = fmaxf(m, mo);
      l = l * __expf(m - mn) + lo * __expf(mo - mn);
      m = mn;
    }
    mrow[b * SS + rowbase + tid] = m;
    linv[b * SS + rowbase + tid] = 1.0f / l;
  }
}

// ---------------- Kernel C2: normalize attn in place + out = P @ V (MFMA bf16) -------
// 32 rows/block, 8 waves = 2 row-groups x 4-way ct split. V reads are contiguous
// 1KB wave loads from the frag-layout VT. Grid (128,4) -> 2 blocks/CU.
__global__ __launch_bounds__(512, 4) void pv_kernel(const short* __restrict__ VT,
                                                    float* __restrict__ attn,
                                                    const float* __restrict__ mrow,
                                                    const float* __restrict__ linv,
                                                    float* __restrict__ outp) {
  __shared__ float sAcc[3][2][16][128];  // 48 KB partial-out exchange
  const int b = blockIdx.y, rowbase = blockIdx.x * 32;
  const int tid = threadIdx.x, wave = tid >> 6, lane = tid & 63;
  const int wg = wave & 1, th = wave >> 1;
  const int l15 = lane & 15, quad = lane >> 4;
  const int row = rowbase + wg * 16 + l15;
  const float m_i = mrow[b * SS + row];
  const float li = linv[b * SS + row];
  float* arow = attn + (size_t)b * SS * SS + (size_t)row * SS + quad * 8;
  const short* vtb = VT + (size_t)b * BSTRIDE + lane * 8;
  floatx4 acc[8];
  #pragma unroll
  for (int nt = 0; nt < 8; ++nt)
    #pragma unroll
    for (int r = 0; r < 4; ++r) acc[nt][r] = 0.f;
  for (int ct = th; ct < 128; ct += 4) {
    const int t0 = ct * 32;
    float4 s0 = *(const float4*)(arow + t0);
    float4 s1 = *(const float4*)(arow + t0 + 4);
    float p[8];
    p[0] = __expf(s0.x - m_i) * li; p[1] = __expf(s0.y - m_i) * li;
    p[2] = __expf(s0.z - m_i) * li; p[3] = __expf(s0.w - m_i) * li;
    p[4] = __expf(s1.x - m_i) * li; p[5] = __expf(s1.y - m_i) * li;
    p[6] = __expf(s1.z - m_i) * li; p[7] = __expf(s1.w - m_i) * li;
    *(float4*)(arow + t0) = make_float4(p[0], p[1], p[2], p[3]);
    *(float4*)(arow + t0 + 4) = make_float4(p[4], p[5], p[6], p[7]);
    short8 a;
    #pragma unroll
    for (int j = 0; j < 8; ++j) a[j] = f2bf(p[j]);
    const short* vtc = vtb + (size_t)ct * 4096;
    #pragma unroll
    for (int nt = 0; nt < 8; ++nt) {
      short8 bf = *(const short8*)(vtc + nt * 512);
      acc[nt] = __builtin_amdgcn_mfma_f32_16x16x32_bf16(a, bf, acc[nt], 0, 0, 0);
    }
  }
  if (th > 0) {
    #pragma unroll
    for (int nt = 0; nt < 8; ++nt)
      #pragma unroll
      for (int r = 0; r < 4; ++r)
        sAcc[th - 1][wg][quad * 4 + r][nt * 16 + l15] = acc[nt][r];
  }
  __syncthreads();
  if (th == 0) {
    #pragma unroll
    for (int nt = 0; nt < 8; ++nt)
      #pragma unroll
      for (int r = 0; r < 4; ++r) {
        const int rr = quad * 4 + r, cc = nt * 16 + l15;
        outp[((size_t)b * SS + rowbase + wg * 16 + rr) * DKk + cc] =
            acc[nt][r] + sAcc[0][wg][rr][cc] + sAcc[1][wg][rr][cc] + sAcc[2][wg][rr][cc];
      }
  }
}

extern "C" void kernel_launch(void* const* d_in, const int* in_sizes, int n_in,
                              void* d_out, int out_size, void* d_ws, size_t ws_size,
                              hipStream_t stream) {
  const float* x  = (const float*)d_in[0];
  const float* tp = (const float*)d_in[1];
  const float* Wq = (const float*)d_in[2];
  const float* bq = (const float*)d_in[3];
  const float* Wk = (const float*)d_in[4];
  const float* bk = (const float*)d_in[5];
  const float* Wv = (const float*)d_in[6];
  const float* bv = (const float*)d_in[7];
  const float* Wt = (const float*)d_in[8];
  const float* bt = (const float*)d_in[9];
  float* out  = (float*)d_out;
  float* attn = out + (size_t)BB * SS * DKk;
  float* ws = (float*)d_ws;
  float* Tws  = ws;                         // 65536
  float* bqt  = ws + 65536;                 // 512
  float* Wqp  = ws + 66048;                 // 524288
  short* QTh  = (short*)(ws + 590336);
  short* QTl  = (short*)(ws + 1638912);
  short* Kh   = (short*)(ws + 2687488);
  short* Kl   = (short*)(ws + 3736064);
  short* VT   = (short*)(ws + 4784640);
  float* mrow = ws + 5833216;
  float* lin  = ws + 5849600;

  temb_kernel<<<dim3(8, 4), 256, 0, stream>>>(tp, Wt, bt, bq, Tws, bqt);
  wqp_kernel<<<dim3(1024, 4), 128, 0, stream>>>(Wq, Tws, Wqp);
  proj_kernel<<<dim3(256, 6), 256, 0, stream>>>(x, Wqp, bqt, Wk, bk, Wv, bv,
                                                QTh, QTl, Kh, Kl, VT);
  score_kernel<<<dim3(128, 4), 256, 0, stream>>>(QTh, QTl, Kh, Kl, attn, mrow, lin);
  pv_kernel<<<dim3(128, 4), 512, 0, stream>>>(VT, attn, mrow, lin, out);
}

// Round 5
// 699.725 us; speedup vs baseline: 1.7407x; 1.1726x over previous
//
#include <hip/hip_runtime.h>
#include <math.h>

#define BB 4
#define SS 4096
#define DD 1024
#define TPp 16
#define TEe 64
#define DKk 128

typedef __attribute__((ext_vector_type(8))) short short8;
typedef __attribute__((ext_vector_type(4))) float floatx4;
typedef __attribute__((ext_vector_type(16))) float floatx16;

#define BSTRIDE 524288   // 4096*128 shorts per batch for frag-layout arrays
#define WFRAG 131072     // shorts per weight matrix in B-frag layout (1024x128)

// bf16 helpers (RNE, branchless)
static __device__ inline short f2bf(float f) {
  union { float f; unsigned u; } v; v.f = f;
  unsigned r = v.u + 0x7fff + ((v.u >> 16) & 1);
  return (short)(r >> 16);
}
static __device__ inline float bf2f(short s) {
  union { unsigned u; float f; } v; v.u = ((unsigned)(unsigned short)s) << 16;
  return v.f;
}

// ---------------- Kernel A1: E = tp@Wt + bt ; T_scaled ; bqt = bq@T ----------------
__global__ __launch_bounds__(256) void temb_kernel(const float* __restrict__ tp,
                                                   const float* __restrict__ Wt,
                                                   const float* __restrict__ bt,
                                                   const float* __restrict__ bq,
                                                   float* __restrict__ Tws,
                                                   float* __restrict__ bqtws) {
  __shared__ float sE[TPp * DKk];
  __shared__ float sB[TPp];
  __shared__ float red[256];
  const int p = blockIdx.x, b = blockIdx.y;
  const int tid = threadIdx.x;
  float lsq = 0.f;
  for (int l = 0; l < 8; ++l) {
    int idx = tid + 256 * l;
    int i = idx >> 7, j = idx & 127;
    float a = bt[j];
    for (int c = 0; c < TEe; ++c)
      a += tp[((size_t)b * TPp + i) * TEe + c] * Wt[c * DKk + j];
    sE[idx] = a;
    lsq += a * a;
  }
  red[tid] = lsq;
  __syncthreads();
  for (int s2 = 128; s2 > 0; s2 >>= 1) {
    if (tid < s2) red[tid] += red[tid + s2];
    __syncthreads();
  }
  const float total = red[0];
  const float scale = (float)SS / (sqrtf((float)SS * total) + 1e-8f);
  if (tid < TPp) {
    float a = 0.f;
    for (int d2 = 0; d2 < DKk; ++d2) a += bq[d2] * sE[tid * DKk + d2];
    sB[tid] = a;
  }
  __syncthreads();
  for (int l = 0; l < 8; ++l) {
    int idx = p * 2048 + tid + 256 * l;
    int d2 = idx >> 7, e = idx & 127;
    float a = 0.f;
    #pragma unroll
    for (int t = 0; t < TPp; ++t) a += sE[t * DKk + d2] * sE[t * DKk + e];
    Tws[(size_t)b * DKk * DKk + idx] = scale * a;
  }
  if (p == 0 && tid < DKk) {
    float a = 0.f;
    #pragma unroll
    for (int t = 0; t < TPp; ++t) a += sB[t] * sE[t * DKk + tid];
    bqtws[b * DKk + tid] = scale * a;
  }
}

// ---------------- Kernel A2: Wqp[b] = Wq @ T[b], written directly as hi/lo B-frags --
// B-frag layout (32x32x16 B operand), per matrix: off(k,n) =
//   ((n>>5)*64 + (k>>4))*512 + (32*((k>>3)&1) + (n&31))*8 + (k&7)
__global__ __launch_bounds__(128) void wqp_kernel(const float* __restrict__ Wq,
                                                  const float* __restrict__ Tws,
                                                  short* __restrict__ WqphF,
                                                  short* __restrict__ WqplF) {
  __shared__ float sW[DKk];
  const int m = blockIdx.x, b = blockIdx.y;   // m = k-index of Wqp
  const int e = threadIdx.x;                  // n-index
  sW[e] = Wq[(size_t)m * DKk + e];
  __syncthreads();
  const float* Tb = Tws + (size_t)b * DKk * DKk;
  float a = 0.f;
  #pragma unroll 8
  for (int d2 = 0; d2 < DKk; ++d2) a += sW[d2] * Tb[d2 * DKk + e];
  const size_t off = (size_t)b * WFRAG +
      (size_t)((e >> 5) * 64 + (m >> 4)) * 512 + (32 * ((m >> 3) & 1) + (e & 31)) * 8 +
      (m & 7);
  short hh = f2bf(a);
  WqphF[off] = hh;
  WqplF[off] = f2bf(a - bf2f(hh));
}

// ---------------- Kernel A3: Wk/Wv -> hi/lo B-frags ----------------
__global__ __launch_bounds__(256) void wcast_kernel(const float* __restrict__ Wk,
                                                    const float* __restrict__ Wv,
                                                    short* __restrict__ WkhF,
                                                    short* __restrict__ WklF,
                                                    short* __restrict__ WvhF,
                                                    short* __restrict__ WvlF) {
  const float* W = blockIdx.y ? Wv : Wk;
  short* H = blockIdx.y ? WvhF : WkhF;
  short* L = blockIdx.y ? WvlF : WklF;
  const int ks = blockIdx.x;                     // 0..63
  const int wave = threadIdx.x >> 6, lane = threadIdx.x & 63;
  const int n = wave * 32 + (lane & 31);
  const int k0 = ks * 16 + (lane >> 5) * 8;
  short8 h, l;
  #pragma unroll
  for (int j = 0; j < 8; ++j) {
    float v = W[(size_t)(k0 + j) * DKk + n];
    short hh = f2bf(v);
    h[j] = hh;
    l[j] = f2bf(v - bf2f(hh));
  }
  const size_t off = ((size_t)wave * 64 + ks) * 512 + lane * 8;
  *(short8*)&H[off] = h;
  *(short8*)&L[off] = l;
}

// ---------------- Kernel B: fused MFMA projection (split bf16, 3 regions/block) -----
// Block = 32 rows x (QT,K,V all 128 cols). Wave w handles col-tile [32w,32w+32).
// x staged to LDS per 64-k chunk (register-prefetched), converted to hi/lo A-frags
// once per wave per kstep, used by 9 MFMAs (3 regions x 3 split products).
__global__ __launch_bounds__(256, 2) void proj_kernel(const float* __restrict__ x,
                                                      const short* __restrict__ WqphF,
                                                      const short* __restrict__ WqplF,
                                                      const short* __restrict__ WkhF,
                                                      const short* __restrict__ WklF,
                                                      const short* __restrict__ WvhF,
                                                      const short* __restrict__ WvlF,
                                                      const float* __restrict__ bqt,
                                                      const float* __restrict__ bk,
                                                      const float* __restrict__ bv,
                                                      short* __restrict__ QTh,
                                                      short* __restrict__ QTl,
                                                      short* __restrict__ Kh,
                                                      short* __restrict__ Kl,
                                                      short* __restrict__ VT) {
  __shared__ float xs[32 * 66];   // 32 rows x 64 k, stride 66 (2-way-free banks)
  const int tileG = blockIdx.x;             // 0..511
  const int b = tileG >> 7, tileL = tileG & 127;
  const int rowbase = tileG * 32;
  const int tid = threadIdx.x, wave = tid >> 6, lane = tid & 63;
  const int l31 = lane & 31, half = lane >> 5;
  const short* B0h = WqphF + (size_t)b * WFRAG + (size_t)wave * 32768;
  const short* B0l = WqplF + (size_t)b * WFRAG + (size_t)wave * 32768;
  const short* B1h = WkhF + (size_t)wave * 32768;
  const short* B1l = WklF + (size_t)wave * 32768;
  const short* B2h = WvhF + (size_t)wave * 32768;
  const short* B2l = WvlF + (size_t)wave * 32768;
  floatx16 acc0, acc1, acc2;
  #pragma unroll
  for (int r = 0; r < 16; ++r) { acc0[r] = 0.f; acc1[r] = 0.f; acc2[r] = 0.f; }
  const int sr = tid >> 3, sc = (tid & 7) * 8;
  const float* xrow = &x[(size_t)(rowbase + sr) * DD + sc];
  float4 p0 = *(const float4*)xrow;
  float4 p1 = *(const float4*)(xrow + 4);
  for (int kc = 0; kc < 16; ++kc) {
    __syncthreads();
    float* dst = &xs[sr * 66 + sc];
    dst[0] = p0.x; dst[1] = p0.y; dst[2] = p0.z; dst[3] = p0.w;
    dst[4] = p1.x; dst[5] = p1.y; dst[6] = p1.z; dst[7] = p1.w;
    if (kc < 15) {
      p0 = *(const float4*)(xrow + (kc + 1) * 64);
      p1 = *(const float4*)(xrow + (kc + 1) * 64 + 4);
    }
    __syncthreads();
    #pragma unroll
    for (int ks = 0; ks < 4; ++ks) {
      const float* ap = &xs[l31 * 66 + ks * 16 + half * 8];
      short8 aH, aL;
      #pragma unroll
      for (int j = 0; j < 8; ++j) {
        float v = ap[j];
        short hh = f2bf(v);
        aH[j] = hh;
        aL[j] = f2bf(v - bf2f(hh));
      }
      const size_t boff = (size_t)(kc * 4 + ks) * 512 + lane * 8;
      short8 bh, bl;
      bh = *(const short8*)(B0h + boff); bl = *(const short8*)(B0l + boff);
      acc0 = __builtin_amdgcn_mfma_f32_32x32x16_bf16(aL, bh, acc0, 0, 0, 0);
      acc0 = __builtin_amdgcn_mfma_f32_32x32x16_bf16(aH, bl, acc0, 0, 0, 0);
      acc0 = __builtin_amdgcn_mfma_f32_32x32x16_bf16(aH, bh, acc0, 0, 0, 0);
      bh = *(const short8*)(B1h + boff); bl = *(const short8*)(B1l + boff);
      acc1 = __builtin_amdgcn_mfma_f32_32x32x16_bf16(aL, bh, acc1, 0, 0, 0);
      acc1 = __builtin_amdgcn_mfma_f32_32x32x16_bf16(aH, bl, acc1, 0, 0, 0);
      acc1 = __builtin_amdgcn_mfma_f32_32x32x16_bf16(aH, bh, acc1, 0, 0, 0);
      bh = *(const short8*)(B2h + boff); bl = *(const short8*)(B2l + boff);
      acc2 = __builtin_amdgcn_mfma_f32_32x32x16_bf16(aL, bh, acc2, 0, 0, 0);
      acc2 = __builtin_amdgcn_mfma_f32_32x32x16_bf16(aH, bl, acc2, 0, 0, 0);
      acc2 = __builtin_amdgcn_mfma_f32_32x32x16_bf16(aH, bh, acc2, 0, 0, 0);
    }
  }
  // Epilogue. C/D: col(n) = lane&31 (+32*wave), row(t) = (reg&3)+8*(reg>>2)+4*half.
  const int f = wave * 32 + l31;
  const int fks = f >> 4, fh = (f >> 3) & 1, fj = f & 7;
  const size_t qkbase =
      (size_t)b * BSTRIDE + (size_t)tileL * 4096 + (size_t)fks * 512 + fj;
  const float biasq = bqt[b * DKk + f];
  const float biask = bk[f];
  #pragma unroll
  for (int reg = 0; reg < 16; ++reg) {
    const int t = (reg & 3) + 8 * (reg >> 2) + 4 * half;
    const size_t off = qkbase + (size_t)(fh * 32 + t) * 8;
    float v = acc0[reg] + biasq;
    short hh = f2bf(v);
    QTh[off] = hh;
    QTl[off] = f2bf(v - bf2f(hh));
    v = acc1[reg] + biask;
    hh = f2bf(v);
    Kh[off] = hh;
    Kl[off] = f2bf(v - bf2f(hh));
  }
  const float biasv = bv[f];
  const int n15 = f & 15, ntt = f >> 4;
  #pragma unroll
  for (int g = 0; g < 4; ++g) {
    short4 s4;
    s4.x = f2bf(acc2[4 * g + 0] + biasv);
    s4.y = f2bf(acc2[4 * g + 1] + biasv);
    s4.z = f2bf(acc2[4 * g + 2] + biasv);
    s4.w = f2bf(acc2[4 * g + 3] + biasv);
    const size_t off = (size_t)b * BSTRIDE + (size_t)(tileL * 8 + ntt) * 512 +
                       (size_t)(g * 16 + n15) * 8 + 4 * half;
    *(short4*)&VT[off] = s4;
  }
}

// ---------------- Kernel C1: MFMA scores (split bf16) + nt raw write + m/linv --------
// 1D grid 512, batch pinned to an XCD pair so the 4MB K-frag set stays L2-resident.
__global__ __launch_bounds__(256, 2) void score_kernel(const short* __restrict__ QTh,
                                                       const short* __restrict__ QTl,
                                                       const short* __restrict__ Kh,
                                                       const short* __restrict__ Kl,
                                                       float* __restrict__ attn,
                                                       float* __restrict__ mrow,
                                                       float* __restrict__ linv) {
  __shared__ float smM[4][32], smL[4][32];
  const int id = blockIdx.x;
  const int xcd = id & 7;
  const int b = xcd >> 1;
  const int tile = ((id >> 3) << 1) + (xcd & 1);   // 0..127
  const int rowbase = tile * 32;
  const int tid = threadIdx.x;
  const int wave = tid >> 6, lane = tid & 63;
  const int l31 = lane & 31, half = lane >> 5;
  const float sc = 0.088388347648318447f;  // 1/sqrt(128)
  const size_t qbase = (size_t)b * BSTRIDE + (size_t)tile * 4096 + lane * 8;
  short8 aH[8], aL[8];
  #pragma unroll
  for (int ks = 0; ks < 8; ++ks) {
    aH[ks] = *(const short8*)(QTh + qbase + ks * 512);
    aL[ks] = *(const short8*)(QTl + qbase + ks * 512);
  }
  float m_r[16], l_r[16];
  #pragma unroll
  for (int r = 0; r < 16; ++r) { m_r[r] = -INFINITY; l_r[r] = 0.f; }
  float* attnb = attn + (size_t)b * SS * SS;
  float* srowbase = attnb + (size_t)rowbase * SS + l31;
  for (int ct = wave; ct < 128; ct += 4) {
    const int colbase = ct * 32;
    const size_t kbase = (size_t)b * BSTRIDE + (size_t)ct * 4096 + lane * 8;
    floatx16 acc;
    #pragma unroll
    for (int r = 0; r < 16; ++r) acc[r] = 0.f;
    #pragma unroll
    for (int ks = 0; ks < 8; ++ks) {
      short8 bh = *(const short8*)(Kh + kbase + ks * 512);
      short8 bl = *(const short8*)(Kl + kbase + ks * 512);
      acc = __builtin_amdgcn_mfma_f32_32x32x16_bf16(aH[ks], bh, acc, 0, 0, 0);
      acc = __builtin_amdgcn_mfma_f32_32x32x16_bf16(aH[ks], bl, acc, 0, 0, 0);
      acc = __builtin_amdgcn_mfma_f32_32x32x16_bf16(aL[ks], bh, acc, 0, 0, 0);
    }
    float* srow = srowbase + colbase;
    #pragma unroll
    for (int reg = 0; reg < 16; ++reg) {
      const int row = (reg & 3) + 8 * (reg >> 2) + 4 * half;
      const float s = acc[reg] * sc;
      __builtin_nontemporal_store(s, &srow[(size_t)row * SS]);
      const float mn = fmaxf(m_r[reg], s);
      l_r[reg] = l_r[reg] * __expf(m_r[reg] - mn) + __expf(s - mn);
      m_r[reg] = mn;
    }
  }
  #pragma unroll
  for (int off = 1; off < 32; off <<= 1) {
    #pragma unroll
    for (int reg = 0; reg < 16; ++reg) {
      const float mo = __shfl_xor(m_r[reg], off, 64);
      const float lo = __shfl_xor(l_r[reg], off, 64);
      const float mn = fmaxf(m_r[reg], mo);
      l_r[reg] = l_r[reg] * __expf(m_r[reg] - mn) + lo * __expf(mo - mn);
      m_r[reg] = mn;
    }
  }
  if (l31 == 0) {
    #pragma unroll
    for (int reg = 0; reg < 16; ++reg) {
      const int row = (reg & 3) + 8 * (reg >> 2) + 4 * half;
      smM[wave][row] = m_r[reg];
      smL[wave][row] = l_r[reg];
    }
  }
  __syncthreads();
  if (tid < 32) {
    float m = smM[0][tid], l = smL[0][tid];
    #pragma unroll
    for (int w = 1; w < 4; ++w) {
      const float mo = smM[w][tid], lo = smL[w][tid];
      const float mn = fmaxf(m, mo);
      l = l * __expf(m - mn) + lo * __expf(mo - mn);
      m = mn;
    }
    mrow[b * SS + rowbase + tid] = m;
    linv[b * SS + rowbase + tid] = 1.0f / l;
  }
}

// ---------------- Kernel C2: normalize attn in place + out = P @ V (MFMA bf16) -------
__global__ __launch_bounds__(512, 4) void pv_kernel(const short* __restrict__ VT,
                                                    float* __restrict__ attn,
                                                    const float* __restrict__ mrow,
                                                    const float* __restrict__ linv,
                                                    float* __restrict__ outp) {
  __shared__ float sAcc[3][2][16][128];  // 48 KB partial-out exchange
  const int id = blockIdx.x;
  const int xcd = id & 7;
  const int b = xcd >> 1;
  const int tile = ((id >> 3) << 1) + (xcd & 1);   // 0..127
  const int rowbase = tile * 32;
  const int tid = threadIdx.x, wave = tid >> 6, lane = tid & 63;
  const int wg = wave & 1, th = wave >> 1;
  const int l15 = lane & 15, quad = lane >> 4;
  const int row = rowbase + wg * 16 + l15;
  const float m_i = mrow[b * SS + row];
  const float li = linv[b * SS + row];
  float* arow = attn + (size_t)b * SS * SS + (size_t)row * SS + quad * 8;
  const short* vtb = VT + (size_t)b * BSTRIDE + lane * 8;
  floatx4 acc[8];
  #pragma unroll
  for (int nt = 0; nt < 8; ++nt)
    #pragma unroll
    for (int r = 0; r < 4; ++r) acc[nt][r] = 0.f;
  for (int ct = th; ct < 128; ct += 4) {
    const int t0 = ct * 32;
    floatx4 s0 = __builtin_nontemporal_load((const floatx4*)(arow + t0));
    floatx4 s1 = __builtin_nontemporal_load((const floatx4*)(arow + t0 + 4));
    float p[8];
    p[0] = __expf(s0.x - m_i) * li; p[1] = __expf(s0.y - m_i) * li;
    p[2] = __expf(s0.z - m_i) * li; p[3] = __expf(s0.w - m_i) * li;
    p[4] = __expf(s1.x - m_i) * li; p[5] = __expf(s1.y - m_i) * li;
    p[6] = __expf(s1.z - m_i) * li; p[7] = __expf(s1.w - m_i) * li;
    floatx4 o0 = {p[0], p[1], p[2], p[3]};
    floatx4 o1 = {p[4], p[5], p[6], p[7]};
    __builtin_nontemporal_store(o0, (floatx4*)(arow + t0));
    __builtin_nontemporal_store(o1, (floatx4*)(arow + t0 + 4));
    short8 a;
    #pragma unroll
    for (int j = 0; j < 8; ++j) a[j] = f2bf(p[j]);
    const short* vtc = vtb + (size_t)ct * 4096;
    #pragma unroll
    for (int nt = 0; nt < 8; ++nt) {
      short8 bf = *(const short8*)(vtc + nt * 512);
      acc[nt] = __builtin_amdgcn_mfma_f32_16x16x32_bf16(a, bf, acc[nt], 0, 0, 0);
    }
  }
  if (th > 0) {
    #pragma unroll
    for (int nt = 0; nt < 8; ++nt)
      #pragma unroll
      for (int r = 0; r < 4; ++r)
        sAcc[th - 1][wg][quad * 4 + r][nt * 16 + l15] = acc[nt][r];
  }
  __syncthreads();
  if (th == 0) {
    #pragma unroll
    for (int nt = 0; nt < 8; ++nt)
      #pragma unroll
      for (int r = 0; r < 4; ++r) {
        const int rr = quad * 4 + r, cc = nt * 16 + l15;
        outp[((size_t)b * SS + rowbase + wg * 16 + rr) * DKk + cc] =
            acc[nt][r] + sAcc[0][wg][rr][cc] + sAcc[1][wg][rr][cc] + sAcc[2][wg][rr][cc];
      }
  }
}

extern "C" void kernel_launch(void* const* d_in, const int* in_sizes, int n_in,
                              void* d_out, int out_size, void* d_ws, size_t ws_size,
                              hipStream_t stream) {
  const float* x  = (const float*)d_in[0];
  const float* tp = (const float*)d_in[1];
  const float* Wq = (const float*)d_in[2];
  const float* bq = (const float*)d_in[3];
  const float* Wk = (const float*)d_in[4];
  const float* bk = (const float*)d_in[5];
  const float* Wv = (const float*)d_in[6];
  const float* bv = (const float*)d_in[7];
  const float* Wt = (const float*)d_in[8];
  const float* bt = (const float*)d_in[9];
  float* out  = (float*)d_out;
  float* attn = out + (size_t)BB * SS * DKk;
  float* ws = (float*)d_ws;
  // workspace layout (float offsets)
  float* Tws   = ws;                          // 65536
  float* bqt   = ws + 65536;                  // 512
  short* WqphF = (short*)(ws + 66048);        // 4*131072 shorts = 262144 fl
  short* WqplF = (short*)(ws + 328192);
  short* WkhF  = (short*)(ws + 590336);       // 131072 shorts = 65536 fl
  short* WklF  = (short*)(ws + 655872);
  short* WvhF  = (short*)(ws + 721408);
  short* WvlF  = (short*)(ws + 786944);
  short* QTh   = (short*)(ws + 852480);       // 2097152 shorts = 1048576 fl
  short* QTl   = (short*)(ws + 1901056);
  short* Kh    = (short*)(ws + 2949632);
  short* Kl    = (short*)(ws + 3998208);
  short* VT    = (short*)(ws + 5046784);
  float* mrow  = ws + 6095360;
  float* lin   = ws + 6111744;                // total 6128128 fl = 24.5 MiB

  temb_kernel<<<dim3(8, 4), 256, 0, stream>>>(tp, Wt, bt, bq, Tws, bqt);
  wqp_kernel<<<dim3(1024, 4), 128, 0, stream>>>(Wq, Tws, WqphF, WqplF);
  wcast_kernel<<<dim3(64, 2), 256, 0, stream>>>(Wk, Wv, WkhF, WklF, WvhF, WvlF);
  proj_kernel<<<512, 256, 0, stream>>>(x, WqphF, WqplF, WkhF, WklF, WvhF, WvlF,
                                       bqt, bk, bv, QTh, QTl, Kh, Kl, VT);
  score_kernel<<<512, 256, 0, stream>>>(QTh, QTl, Kh, Kl, attn, mrow, lin);
  pv_kernel<<<512, 512, 0, stream>>>(VT, attn, mrow, lin, out);
}